// Round 10
// baseline (2790.214 us; speedup 1.0000x reference)
//
#include <hip/hip_runtime.h>

#define BB 256
#define TT 2048
#define HD 100

typedef _Float16 h2v __attribute__((ext_vector_type(2)));

__device__ __forceinline__ float fdot2(unsigned w, unsigned h, float c) {
#if __has_builtin(__builtin_amdgcn_fdot2)
    return __builtin_amdgcn_fdot2(__builtin_bit_cast(h2v, w),
                                  __builtin_bit_cast(h2v, h), c, false);
#else
    h2v a = __builtin_bit_cast(h2v, w), b = __builtin_bit_cast(h2v, h);
    c = fmaf((float)a[0], (float)b[0], c);
    c = fmaf((float)a[1], (float)b[1], c);
    return c;
#endif
}
__device__ __forceinline__ unsigned packh2(float a, float b) {
    h2v p; p[0] = (_Float16)a; p[1] = (_Float16)b;
    return __builtin_bit_cast(unsigned, p);
}
__device__ __forceinline__ float rcp_f(float x) {
#if __has_builtin(__builtin_amdgcn_rcpf)
    return __builtin_amdgcn_rcpf(x);
#else
    return 1.0f / x;
#endif
}
// act(x) = m / (1 + e^{-s x}) + d :  (1,1,0)->sigmoid, (2,2,-1)->tanh
__device__ __forceinline__ float act_f(float x, float m, float s, float d) {
    return fmaf(m, rcp_f(1.0f + __expf(-s * x)), d);
}
__device__ __forceinline__ float tanh_f(float x) {
    return fmaf(2.0f, rcp_f(1.0f + __expf(-2.0f * x)), -1.0f);
}

// One persistent block per batch row. 512 threads = 8 waves, 1 block/CU.
//   waves 0-3 (grp0): layer-1 gates (lt<200, rows 2lt,2lt+1) + x loaders (lt 200..231)
//   waves 4-7 (grp1): layer-2 gates
// R10 structural changes vs R7/R9:
//  - h1/h2 state REPLICATED IN REGISTERS per wave (lane<50 holds packed pair
//    `lane`); EVERY wave redundantly runs the c/h update from the gate LDS.
//    The readlane source is the wave's own register -> no LDS load + lgkm
//    stall at the loop head, and exec-full by construction (readlane reads
//    lanes 0..49 only; lanes >=50 hold garbage that is never read).
//  - ONE barrier per step: gates go to double-buffered LDS g1b/g2b[i&1].
//    Write(i, buf i&1) | BARRIER | read(i, buf i&1); iteration i+1 writes
//    buf (i+1)&1, and no wave can reach its i+2 write (buf i&1 again)
//    until all waves passed barrier(i+1), which is after all i reads. Safe.
// Pipeline skew: iteration i computes L1 step i and L2 step i-1.
__global__ __launch_bounds__(512)
__attribute__((amdgpu_flat_work_group_size(512, 512), amdgpu_waves_per_eu(2, 2)))
void lstm_fused(
    const float* __restrict__ x,
    const float* __restrict__ w_ih1, const float* __restrict__ w_hh1,
    const float* __restrict__ b_ih1, const float* __restrict__ b_hh1,
    const float* __restrict__ w_ih2, const float* __restrict__ w_hh2,
    const float* __restrict__ b_ih2, const float* __restrict__ b_hh2,
    const float* __restrict__ fc1_w, const float* __restrict__ fc1_b,
    const float* __restrict__ fc2_w, const float* __restrict__ fc2_b,
    float* __restrict__ out)
{
    const int b    = blockIdx.x;
    const int tid  = threadIdx.x;
    const int lane = tid & 63;
    const int grp  = tid >> 8;        // 0 = L1 waves, 1 = L2 waves (wave-uniform)
    const int lt   = tid & 255;

    __shared__ __align__(16) unsigned xs[2][32][4]; // x chunk, packed f16x2, dbuf
    __shared__ float g1b[2][400];                   // L1 gates, double-buffered
    __shared__ float g2b[2][400];                   // L2 gates, double-buffered
    __shared__ float h2f[HD];
    __shared__ float fca[25];

    const bool isG = lt < 200;                      // gate-store guard only
    const int  gt  = isG ? lt : 199;                // clamped gate thread
    const bool isX = (grp == 0) && (lt >= 200) && (lt < 232);
    const int  xsl = lt - 200;

    unsigned wreg[200];
    float bias0, bias1;
    // replicated per-wave state: lane<50 holds unit pair `lane`
    float c1x = 0.f, c1y = 0.f;                     // L1 cell pair (all waves)
    float c2x = 0.f, c2y = 0.f;                     // L2 cell pair (grp1 waves)
    unsigned h1reg = 0u, h2reg = 0u;                // packed f16x2 h pairs

    const int g0 = 2 * gt, g1r = 2 * gt + 1;
    if (grp == 0) {
        // L1 map: [0..3] x row0 | [4..53] h row0 | [54..57] x row1 | [58..107] h row1
        { const float4* p = (const float4*)(w_ih1 + (size_t)g0 * 8);
          float4 v0 = p[0], v1 = p[1];
          wreg[0] = packh2(v0.x, v0.y); wreg[1] = packh2(v0.z, v0.w);
          wreg[2] = packh2(v1.x, v1.y); wreg[3] = packh2(v1.z, v1.w); }
        { const float4* p = (const float4*)(w_ih1 + (size_t)g1r * 8);
          float4 v0 = p[0], v1 = p[1];
          wreg[54] = packh2(v0.x, v0.y); wreg[55] = packh2(v0.z, v0.w);
          wreg[56] = packh2(v1.x, v1.y); wreg[57] = packh2(v1.z, v1.w); }
        { const float4* p = (const float4*)(w_hh1 + (size_t)g0 * HD);
          #pragma unroll
          for (int q = 0; q < 25; ++q) {
              float4 v = p[q];
              wreg[4 + 2*q] = packh2(v.x, v.y); wreg[5 + 2*q] = packh2(v.z, v.w);
          } }
        { const float4* p = (const float4*)(w_hh1 + (size_t)g1r * HD);
          #pragma unroll
          for (int q = 0; q < 25; ++q) {
              float4 v = p[q];
              wreg[58 + 2*q] = packh2(v.x, v.y); wreg[59 + 2*q] = packh2(v.z, v.w);
          } }
        bias0 = b_ih1[g0] + b_hh1[g0];
        bias1 = b_ih1[g1r] + b_hh1[g1r];
    } else {
        // L2 map: [0..49] wI row0 | [50..99] wI row1 | [100..149] wH row0 | [150..199] wH row1
        { const float4* p = (const float4*)(w_ih2 + (size_t)g0 * HD);
          #pragma unroll
          for (int q = 0; q < 25; ++q) {
              float4 v = p[q];
              wreg[2*q] = packh2(v.x, v.y); wreg[2*q + 1] = packh2(v.z, v.w);
          } }
        { const float4* p = (const float4*)(w_ih2 + (size_t)g1r * HD);
          #pragma unroll
          for (int q = 0; q < 25; ++q) {
              float4 v = p[q];
              wreg[50 + 2*q] = packh2(v.x, v.y); wreg[51 + 2*q] = packh2(v.z, v.w);
          } }
        { const float4* p = (const float4*)(w_hh2 + (size_t)g0 * HD);
          #pragma unroll
          for (int q = 0; q < 25; ++q) {
              float4 v = p[q];
              wreg[100 + 2*q] = packh2(v.x, v.y); wreg[101 + 2*q] = packh2(v.z, v.w);
          } }
        { const float4* p = (const float4*)(w_hh2 + (size_t)g1r * HD);
          #pragma unroll
          for (int q = 0; q < 25; ++q) {
              float4 v = p[q];
              wreg[150 + 2*q] = packh2(v.x, v.y); wreg[151 + 2*q] = packh2(v.z, v.w);
          } }
        bias0 = b_ih2[g0] + b_hh2[g0];
        bias1 = b_ih2[g1r] + b_hh2[g1r];
    }
    // per-thread activation constants (rows 200..299 = g gate -> tanh)
    const bool tg = (gt >= 100) && (gt < 150);
    const float am = tg ? 2.0f : 1.0f;
    const float as = tg ? 2.0f : 1.0f;
    const float ad = tg ? -1.0f : 0.0f;

    if (isX) {   // stage x steps 0..31 into buf 0
        const float4* p = (const float4*)(x + ((size_t)b * TT + xsl) * 8);
        float4 v0 = p[0], v1 = p[1];
        xs[0][xsl][0] = packh2(v0.x, v0.y); xs[0][xsl][1] = packh2(v0.z, v0.w);
        xs[0][xsl][2] = packh2(v1.x, v1.y); xs[0][xsl][3] = packh2(v1.z, v1.w);
    }
    __syncthreads();

    float4 pa = {0,0,0,0}, pb = {0,0,0,0};

    #pragma unroll 1
    for (int i = 0; i <= TT; ++i) {
        const bool pf = ((i & 31) == 0) && (i + 32 < TT);
        const int  bf = i & 1;                      // gate double-buffer index
        // ================= phase 1: gates =================
        if (grp == 0) {
            if (i < TT) {                           // uniform guard
                if (isX && pf) {                    // issue next x chunk
                    const float4* p = (const float4*)(x + ((size_t)b * TT + i + 32 + xsl) * 8);
                    pa = p[0]; pb = p[1];
                }
                const unsigned st = h1reg;          // OWN register (no LDS)
                const unsigned* xq = xs[(i >> 5) & 1][i & 31];
                unsigned x0 = xq[0], x1 = xq[1], x2 = xq[2], x3 = xq[3];
                float a0 = bias0, a1 = bias1, a2 = 0.f, a3 = 0.f;
                a0 = fdot2(wreg[0], x0, a0); a2 = fdot2(wreg[1], x1, a2);
                a0 = fdot2(wreg[2], x2, a0); a2 = fdot2(wreg[3], x3, a2);
                a1 = fdot2(wreg[54], x0, a1); a3 = fdot2(wreg[55], x1, a3);
                a1 = fdot2(wreg[56], x2, a1); a3 = fdot2(wreg[57], x3, a3);
                #pragma unroll
                for (int k = 0; k < 50; ++k) {
                    unsigned hk = (unsigned)__builtin_amdgcn_readlane((int)st, k);
                    if (k & 1) { a2 = fdot2(wreg[4 + k], hk, a2); a3 = fdot2(wreg[58 + k], hk, a3); }
                    else       { a0 = fdot2(wreg[4 + k], hk, a0); a1 = fdot2(wreg[58 + k], hk, a1); }
                }
                float r0 = act_f(a0 + a2, am, as, ad);
                float r1 = act_f(a1 + a3, am, as, ad);
                if (isG) *(float2*)(&g1b[bf][2 * gt]) = make_float2(r0, r1);
            }
        } else {
            if (i >= 1) {                           // uniform guard (L2 step i-1)
                const unsigned cur = h1reg;         // h1(i-1), own register
                const unsigned st2 = h2reg;         // h2(i-2), own register
                float a0 = bias0, a1 = bias1, a2 = 0.f, a3 = 0.f;
                #pragma unroll
                for (int k = 0; k < 50; ++k) {
                    unsigned hk = (unsigned)__builtin_amdgcn_readlane((int)cur, k);
                    if (k & 1) { a2 = fdot2(wreg[k], hk, a2); a3 = fdot2(wreg[50 + k], hk, a3); }
                    else       { a0 = fdot2(wreg[k], hk, a0); a1 = fdot2(wreg[50 + k], hk, a1); }
                }
                #pragma unroll
                for (int k = 0; k < 50; ++k) {
                    unsigned hk = (unsigned)__builtin_amdgcn_readlane((int)st2, k);
                    if (k & 1) { a2 = fdot2(wreg[100 + k], hk, a2); a3 = fdot2(wreg[150 + k], hk, a3); }
                    else       { a0 = fdot2(wreg[100 + k], hk, a0); a1 = fdot2(wreg[150 + k], hk, a1); }
                }
                float r0 = act_f(a0 + a2, am, as, ad);
                float r1 = act_f(a1 + a3, am, as, ad);
                if (isG) *(float2*)(&g2b[bf][2 * gt]) = make_float2(r0, r1);
            }
        }
        __syncthreads();   // the ONLY barrier per step
        // ========= phase 2: replicated state update (no barrier after) =========
        if (i < TT && lane < 50) {                  // L1 update: ALL waves
            const float* g = g1b[bf];
            float2 gi = *(const float2*)(g + 2 * lane);
            float2 gf = *(const float2*)(g + 100 + 2 * lane);
            float2 gg = *(const float2*)(g + 200 + 2 * lane);
            float2 go = *(const float2*)(g + 300 + 2 * lane);
            c1x = gf.x * c1x + gi.x * gg.x;
            c1y = gf.y * c1y + gi.y * gg.y;
            h1reg = packh2(go.x * tanh_f(c1x), go.y * tanh_f(c1y));
        }
        if (grp == 1 && i >= 1 && lane < 50) {      // L2 update: grp1 waves
            const float* g = g2b[bf];
            float2 gi = *(const float2*)(g + 2 * lane);
            float2 gf = *(const float2*)(g + 100 + 2 * lane);
            float2 gg = *(const float2*)(g + 200 + 2 * lane);
            float2 go = *(const float2*)(g + 300 + 2 * lane);
            c2x = gf.x * c2x + gi.x * gg.x;
            c2y = gf.y * c2y + gi.y * gg.y;
            float h0 = go.x * tanh_f(c2x);
            float h1v = go.y * tanh_f(c2y);
            h2reg = packh2(h0, h1v);
            if (i == TT) {                          // all grp1 waves write same values
                h2f[2 * lane] = h0; h2f[2 * lane + 1] = h1v;
            }
        }
        if (isX && pf) {                            // x chunk LDS write
            const int nb2 = ((i >> 5) + 1) & 1;
            xs[nb2][xsl][0] = packh2(pa.x, pa.y); xs[nb2][xsl][1] = packh2(pa.z, pa.w);
            xs[nb2][xsl][2] = packh2(pb.x, pb.y); xs[nb2][xsl][3] = packh2(pb.z, pb.w);
        }
    }
    __syncthreads();

    // ================= FC head (in-block) =================
    if (tid < 25) {
        float a = fc1_b[tid];
        const float* wp = fc1_w + tid * HD;
        #pragma unroll
        for (int k = 0; k < HD; ++k) a += h2f[k] * wp[k];
        fca[tid] = a;
    }
    __syncthreads();
    if (tid == 0) {
        float y = fc2_b[0];
        #pragma unroll
        for (int m = 0; m < 25; ++m) y += fca[m] * fc2_w[m];
        out[b] = y;
    }
}

extern "C" void kernel_launch(void* const* d_in, const int* in_sizes, int n_in,
                              void* d_out, int out_size, void* d_ws, size_t ws_size,
                              hipStream_t stream) {
    const float* x     = (const float*)d_in[0];
    const float* w_ih1 = (const float*)d_in[1];
    const float* w_hh1 = (const float*)d_in[2];
    const float* b_ih1 = (const float*)d_in[3];
    const float* b_hh1 = (const float*)d_in[4];
    const float* w_ih2 = (const float*)d_in[5];
    const float* w_hh2 = (const float*)d_in[6];
    const float* b_ih2 = (const float*)d_in[7];
    const float* b_hh2 = (const float*)d_in[8];
    const float* fc1_w = (const float*)d_in[9];
    const float* fc1_b = (const float*)d_in[10];
    const float* fc2_w = (const float*)d_in[11];
    const float* fc2_b = (const float*)d_in[12];
    float* out = (float*)d_out;

    lstm_fused<<<BB, 512, 0, stream>>>(x, w_ih1, w_hh1, b_ih1, b_hh1,
                                       w_ih2, w_hh2, b_ih2, b_hh2,
                                       fc1_w, fc1_b, fc2_w, fc2_b, out);
}

// Round 11
// 2743.534 us; speedup vs baseline: 1.0170x; 1.0170x over previous
//
#include <hip/hip_runtime.h>

#define BB 256
#define TT 2048
#define HD 100

typedef _Float16 h2v __attribute__((ext_vector_type(2)));

__device__ __forceinline__ float fdot2(unsigned w, unsigned h, float c) {
#if __has_builtin(__builtin_amdgcn_fdot2)
    return __builtin_amdgcn_fdot2(__builtin_bit_cast(h2v, w),
                                  __builtin_bit_cast(h2v, h), c, false);
#else
    h2v a = __builtin_bit_cast(h2v, w), b = __builtin_bit_cast(h2v, h);
    c = fmaf((float)a[0], (float)b[0], c);
    c = fmaf((float)a[1], (float)b[1], c);
    return c;
#endif
}
__device__ __forceinline__ unsigned packh2(float a, float b) {
    h2v p; p[0] = (_Float16)a; p[1] = (_Float16)b;
    return __builtin_bit_cast(unsigned, p);
}
__device__ __forceinline__ float rcp_f(float x) {
#if __has_builtin(__builtin_amdgcn_rcpf)
    return __builtin_amdgcn_rcpf(x);
#else
    return 1.0f / x;
#endif
}
__device__ __forceinline__ float sigmoid_f(float x) { return rcp_f(1.0f + __expf(-x)); }
__device__ __forceinline__ float tanh_f(float x) {
    return fmaf(2.0f, rcp_f(1.0f + __expf(-2.0f * x)), -1.0f);
}
// act(x) = m * sigmoid(s*x) + d : (1,1,0)->sigmoid, (2,2,-1)->tanh
__device__ __forceinline__ float act_f(float x, float m, float s, float d) {
    return fmaf(m, rcp_f(1.0f + __expf(-s * x)), d);
}

// One persistent block per batch row. 768 threads = 12 waves = 3/SIMD.
// amdgpu_waves_per_eu(3,3) pins the allocator budget to 512/3 = 170 regs/wave
// (per-SIMD unified RF = 512 wave-regs; R8 without the pin budgeted 6 waves/EU
// -> 84 regs -> 32MB scratch). Max per-thread array here is 108 u32, so all
// weights become ARCH-register-resident: no AGPR accvgpr_read tax (R7/R9/R10
// ceiling), no spills.
// Wave-aligned groups (grp = tid>>8, uniform):
//   grp0 (waves 0-3):  L2 wI partial: rows 2gt,2gt+1 of w_ih2 . h1  (100 u32)
//                      spare lanes lt 200..249: L1 c/h update
//   grp1 (waves 4-7):  L2 wH partial: w_hh2 . h2                   (100 u32)
//                      spare lanes lt 200..249: L2 sum+act+c/h update
//   grp2 (waves 8-11): L1 full gate: w_ih1 . x + w_hh1 . h1        (108 u32)
//                      spare lanes lt 200..231: x chunk loaders
// Pipeline skew: iteration i computes L1 step i and L2 step i-1.
// readlane ignores EXEC: every readlane source (st) is loaded by all 64
// lanes under wave-uniform control flow only (R3/R4 lesson).
__global__ __launch_bounds__(768)
__attribute__((amdgpu_waves_per_eu(3, 3)))
void lstm_fused(
    const float* __restrict__ x,
    const float* __restrict__ w_ih1, const float* __restrict__ w_hh1,
    const float* __restrict__ b_ih1, const float* __restrict__ b_hh1,
    const float* __restrict__ w_ih2, const float* __restrict__ w_hh2,
    const float* __restrict__ b_ih2, const float* __restrict__ b_hh2,
    const float* __restrict__ fc1_w, const float* __restrict__ fc1_b,
    const float* __restrict__ fc2_w, const float* __restrict__ fc2_b,
    float* __restrict__ out)
{
    const int b    = blockIdx.x;
    const int tid  = threadIdx.x;
    const int lane = tid & 63;
    const int grp  = tid >> 8;        // wave-uniform (groups are 4 waves)
    const int lt   = tid & 255;

    __shared__ unsigned h1p[64];                    // h1 state, packed f16x2
    __shared__ unsigned h2p[64];                    // h2 state, packed f16x2
    __shared__ __align__(16) unsigned xs[2][32][4]; // x chunk, packed, dbuf
    __shared__ float pI[400];                       // L2 wI partials (by row)
    __shared__ float pH[400];                       // L2 wH partials (by row)
    __shared__ float g1[400];                       // L1 activated gates (by row)
    __shared__ float h2f[HD];
    __shared__ float fca[25];

    const bool isGate = lt < 200;                   // store guard only
    const int  gt  = isGate ? lt : 199;             // clamped row-pair id
    const bool isU = (lt >= 200) && (lt < 250);     // update role (spares)
    const int  u   = lt - 200;                      // unit pair 0..49
    const bool isX = (grp == 2) && (lt >= 200) && (lt < 232);
    const int  xsl = lt - 200;                      // x slot 0..31

    unsigned wreg[108];
    float bias0 = 0.f, bias1 = 0.f;
    float cc0 = 0.f, cc1 = 0.f;                     // cell state (update lanes)

    const int g0 = 2 * gt, g1r = 2 * gt + 1;
    if (grp == 0) {
        // wI rows: row0 -> wreg[0..49], row1 -> wreg[50..99]
        { const float4* p = (const float4*)(w_ih2 + (size_t)g0 * HD);
          #pragma unroll
          for (int q = 0; q < 25; ++q) {
              float4 v = p[q];
              wreg[2*q] = packh2(v.x, v.y); wreg[2*q+1] = packh2(v.z, v.w);
          } }
        { const float4* p = (const float4*)(w_ih2 + (size_t)g1r * HD);
          #pragma unroll
          for (int q = 0; q < 25; ++q) {
              float4 v = p[q];
              wreg[50 + 2*q] = packh2(v.x, v.y); wreg[51 + 2*q] = packh2(v.z, v.w);
          } }
        bias0 = b_ih2[g0] + b_hh2[g0];
        bias1 = b_ih2[g1r] + b_hh2[g1r];
    } else if (grp == 1) {
        // wH rows: row0 -> wreg[0..49], row1 -> wreg[50..99]; bias stays 0
        { const float4* p = (const float4*)(w_hh2 + (size_t)g0 * HD);
          #pragma unroll
          for (int q = 0; q < 25; ++q) {
              float4 v = p[q];
              wreg[2*q] = packh2(v.x, v.y); wreg[2*q+1] = packh2(v.z, v.w);
          } }
        { const float4* p = (const float4*)(w_hh2 + (size_t)g1r * HD);
          #pragma unroll
          for (int q = 0; q < 25; ++q) {
              float4 v = p[q];
              wreg[50 + 2*q] = packh2(v.x, v.y); wreg[51 + 2*q] = packh2(v.z, v.w);
          } }
    } else {
        // L1: row0: x pairs wreg[0..3], h pairs wreg[4..53];
        //     row1: x pairs wreg[54..57], h pairs wreg[58..107]
        { const float4* p = (const float4*)(w_ih1 + (size_t)g0 * 8);
          float4 v0 = p[0], v1 = p[1];
          wreg[0] = packh2(v0.x, v0.y); wreg[1] = packh2(v0.z, v0.w);
          wreg[2] = packh2(v1.x, v1.y); wreg[3] = packh2(v1.z, v1.w); }
        { const float4* p = (const float4*)(w_ih1 + (size_t)g1r * 8);
          float4 v0 = p[0], v1 = p[1];
          wreg[54] = packh2(v0.x, v0.y); wreg[55] = packh2(v0.z, v0.w);
          wreg[56] = packh2(v1.x, v1.y); wreg[57] = packh2(v1.z, v1.w); }
        { const float4* p = (const float4*)(w_hh1 + (size_t)g0 * HD);
          #pragma unroll
          for (int q = 0; q < 25; ++q) {
              float4 v = p[q];
              wreg[4 + 2*q] = packh2(v.x, v.y); wreg[5 + 2*q] = packh2(v.z, v.w);
          } }
        { const float4* p = (const float4*)(w_hh1 + (size_t)g1r * HD);
          #pragma unroll
          for (int q = 0; q < 25; ++q) {
              float4 v = p[q];
              wreg[58 + 2*q] = packh2(v.x, v.y); wreg[59 + 2*q] = packh2(v.z, v.w);
          } }
        bias0 = b_ih1[g0] + b_hh1[g0];
        bias1 = b_ih1[g1r] + b_hh1[g1r];
    }
    // L1 inline-activation constants (rows 200..299 = g gate -> tanh)
    const bool tg = (gt >= 100) && (gt < 150);
    const float am = tg ? 2.0f : 1.0f;
    const float as = tg ? 2.0f : 1.0f;
    const float ad = tg ? -1.0f : 0.0f;

    if (tid < 64) { h1p[tid] = 0u; h2p[tid] = 0u; }
    if (isX) {   // stage x steps 0..31 into buf 0
        const float4* p = (const float4*)(x + ((size_t)b * TT + xsl) * 8);
        float4 v0 = p[0], v1 = p[1];
        xs[0][xsl][0] = packh2(v0.x, v0.y); xs[0][xsl][1] = packh2(v0.z, v0.w);
        xs[0][xsl][2] = packh2(v1.x, v1.y); xs[0][xsl][3] = packh2(v1.z, v1.w);
    }
    __syncthreads();

    float4 pa = {0,0,0,0}, pb = {0,0,0,0};

    #pragma unroll 1
    for (int i = 0; i <= TT; ++i) {
        const bool pf = ((i & 31) == 0) && (i + 32 < TT);
        // readlane source: loaded by ALL lanes of every wave
        const unsigned st = (grp == 1) ? h2p[lane] : h1p[lane];
        // ================= phase 1: dot products =================
        if (grp == 2) {
            if (i < TT) {                           // uniform guard
                if (isX && pf) {                    // issue next x chunk loads
                    const float4* p = (const float4*)(x + ((size_t)b * TT + i + 32 + xsl) * 8);
                    pa = p[0]; pb = p[1];
                }
                const unsigned* xq = xs[(i >> 5) & 1][i & 31];
                unsigned x0 = xq[0], x1 = xq[1], x2 = xq[2], x3 = xq[3];
                float a0 = bias0, a1 = bias1, a2 = 0.f, a3 = 0.f;
                a0 = fdot2(wreg[0], x0, a0); a2 = fdot2(wreg[1], x1, a2);
                a0 = fdot2(wreg[2], x2, a0); a2 = fdot2(wreg[3], x3, a2);
                a1 = fdot2(wreg[54], x0, a1); a3 = fdot2(wreg[55], x1, a3);
                a1 = fdot2(wreg[56], x2, a1); a3 = fdot2(wreg[57], x3, a3);
                #pragma unroll
                for (int k = 0; k < 50; ++k) {
                    unsigned hk = (unsigned)__builtin_amdgcn_readlane((int)st, k);
                    if (k & 1) { a2 = fdot2(wreg[4 + k], hk, a2); a3 = fdot2(wreg[58 + k], hk, a3); }
                    else       { a0 = fdot2(wreg[4 + k], hk, a0); a1 = fdot2(wreg[58 + k], hk, a1); }
                }
                float r0 = act_f(a0 + a2, am, as, ad);
                float r1 = act_f(a1 + a3, am, as, ad);
                if (isGate) *(float2*)(g1 + 2 * gt) = make_float2(r0, r1);
            }
        } else {
            if (i >= 1) {                           // uniform guard (L2 step i-1)
                float a0 = bias0, a1 = bias1, a2 = 0.f, a3 = 0.f;
                #pragma unroll
                for (int k = 0; k < 50; ++k) {
                    unsigned hk = (unsigned)__builtin_amdgcn_readlane((int)st, k);
                    if (k & 1) { a2 = fdot2(wreg[k], hk, a2); a3 = fdot2(wreg[50 + k], hk, a3); }
                    else       { a0 = fdot2(wreg[k], hk, a0); a1 = fdot2(wreg[50 + k], hk, a1); }
                }
                float* dst = (grp == 0) ? pI : pH;
                if (isGate) *(float2*)(dst + 2 * gt) = make_float2(a0 + a2, a1 + a3);
            }
        }
        __syncthreads();
        // ================= phase 2: state updates =================
        if (grp == 0) {
            if (i < TT && isU) {                    // L1 c/h update
                const int j = 2 * u;
                float2 gi = *(const float2*)(g1 + j);
                float2 gf = *(const float2*)(g1 + 100 + j);
                float2 gg = *(const float2*)(g1 + 200 + j);
                float2 go = *(const float2*)(g1 + 300 + j);
                cc0 = gf.x * cc0 + gi.x * gg.x;
                cc1 = gf.y * cc1 + gi.y * gg.y;
                h1p[u] = packh2(go.x * tanh_f(cc0), go.y * tanh_f(cc1));
            }
        } else if (grp == 1) {
            if (i >= 1 && isU) {                    // L2 sum+act+c/h update
                const int j = 2 * u;
                float2 sIi = *(const float2*)(pI + j);
                float2 sHi = *(const float2*)(pH + j);
                float2 sIf = *(const float2*)(pI + 100 + j);
                float2 sHf = *(const float2*)(pH + 100 + j);
                float2 sIg = *(const float2*)(pI + 200 + j);
                float2 sHg = *(const float2*)(pH + 200 + j);
                float2 sIo = *(const float2*)(pI + 300 + j);
                float2 sHo = *(const float2*)(pH + 300 + j);
                float gi0 = sigmoid_f(sIi.x + sHi.x), gi1 = sigmoid_f(sIi.y + sHi.y);
                float gf0 = sigmoid_f(sIf.x + sHf.x), gf1 = sigmoid_f(sIf.y + sHf.y);
                float gg0 = tanh_f(sIg.x + sHg.x),    gg1 = tanh_f(sIg.y + sHg.y);
                float go0 = sigmoid_f(sIo.x + sHo.x), go1 = sigmoid_f(sIo.y + sHo.y);
                cc0 = gf0 * cc0 + gi0 * gg0;
                cc1 = gf1 * cc1 + gi1 * gg1;
                float h0 = go0 * tanh_f(cc0);
                float h1v = go1 * tanh_f(cc1);
                h2p[u] = packh2(h0, h1v);
                if (i == TT) { h2f[j] = h0; h2f[j + 1] = h1v; }
            }
        } else {
            if (isX && pf) {                        // x chunk LDS write
                const int nb2 = ((i >> 5) + 1) & 1;
                xs[nb2][xsl][0] = packh2(pa.x, pa.y); xs[nb2][xsl][1] = packh2(pa.z, pa.w);
                xs[nb2][xsl][2] = packh2(pb.x, pb.y); xs[nb2][xsl][3] = packh2(pb.z, pb.w);
            }
        }
        __syncthreads();
    }

    // ================= FC head (in-block) =================
    if (tid < 25) {
        float a = fc1_b[tid];
        const float* wp = fc1_w + tid * HD;
        #pragma unroll
        for (int k = 0; k < HD; ++k) a += h2f[k] * wp[k];
        fca[tid] = a;
    }
    __syncthreads();
    if (tid == 0) {
        float y = fc2_b[0];
        #pragma unroll
        for (int m = 0; m < 25; ++m) y += fca[m] * fc2_w[m];
        out[b] = y;
    }
}

extern "C" void kernel_launch(void* const* d_in, const int* in_sizes, int n_in,
                              void* d_out, int out_size, void* d_ws, size_t ws_size,
                              hipStream_t stream) {
    const float* x     = (const float*)d_in[0];
    const float* w_ih1 = (const float*)d_in[1];
    const float* w_hh1 = (const float*)d_in[2];
    const float* b_ih1 = (const float*)d_in[3];
    const float* b_hh1 = (const float*)d_in[4];
    const float* w_ih2 = (const float*)d_in[5];
    const float* w_hh2 = (const float*)d_in[6];
    const float* b_ih2 = (const float*)d_in[7];
    const float* b_hh2 = (const float*)d_in[8];
    const float* fc1_w = (const float*)d_in[9];
    const float* fc1_b = (const float*)d_in[10];
    const float* fc2_w = (const float*)d_in[11];
    const float* fc2_b = (const float*)d_in[12];
    float* out = (float*)d_out;

    lstm_fused<<<BB, 768, 0, stream>>>(x, w_ih1, w_hh1, b_ih1, b_hh1,
                                       w_ih2, w_hh2, b_ih2, b_hh2,
                                       fc1_w, fc1_b, fc2_w, fc2_b, out);
}